// Round 1
// baseline (1263.463 us; speedup 1.0000x reference)
//
#include <hip/hip_runtime.h>

#define NB 100000
#define NG 20000
#define EL 1000000
#define EX 200000

static __device__ __forceinline__ int uni(int x) { return __builtin_amdgcn_readfirstlane(x); }

// ---- edge-degree count: cnt[dst[i]] += 1 ----
__global__ void count_kernel(const int* __restrict__ dst, float* __restrict__ cnt, int E) {
    int i = blockIdx.x * blockDim.x + threadIdx.x;
    if (i < E) atomicAdd(&cnt[dst[i]], 1.0f);
}

// ---- in-place: c = 1 / max(c, 1) ----
__global__ void inv_kernel(float* __restrict__ c, int n) {
    int i = blockIdx.x * blockDim.x + threadIdx.x;
    if (i < n) c[i] = 1.0f / fmaxf(c[i], 1.0f);
}

// ---- t_a = h @ Wa ; t_b = h @ Wb  (64x64 weights in registers, lane = out col) ----
__global__ __launch_bounds__(256) void transform2_kernel(
    const float* __restrict__ h, const float* __restrict__ Wa, const float* __restrict__ Wb,
    float* __restrict__ ta, float* __restrict__ tb, int n)
{
    const int lane = threadIdx.x & 63;
    const int wave = blockIdx.x * (blockDim.x >> 6) + (threadIdx.x >> 6);
    const int nWaves = gridDim.x * (blockDim.x >> 6);
    float wa[64], wb[64];
#pragma unroll
    for (int k = 0; k < 64; ++k) { wa[k] = Wa[k * 64 + lane]; wb[k] = Wb[k * 64 + lane]; }
    for (int row = uni(wave); row < n; row += nWaves) {
        const float* __restrict__ hr = h + (size_t)row * 64;
        float a = 0.f, b = 0.f;
#pragma unroll
        for (int k = 0; k < 64; ++k) {
            float hk = hr[k];  // wave-uniform -> scalar load
            a += hk * wa[k];
            b += hk * wb[k];
        }
        ta[(size_t)row * 64 + lane] = a;
        tb[(size_t)row * 64 + lane] = b;
    }
}

// ---- t = h @ W (single output) ----
__global__ __launch_bounds__(256) void transform1_kernel(
    const float* __restrict__ h, const float* __restrict__ W, float* __restrict__ t, int n)
{
    const int lane = threadIdx.x & 63;
    const int wave = blockIdx.x * (blockDim.x >> 6) + (threadIdx.x >> 6);
    const int nWaves = gridDim.x * (blockDim.x >> 6);
    float w[64];
#pragma unroll
    for (int k = 0; k < 64; ++k) w[k] = W[k * 64 + lane];
    for (int row = uni(wave); row < n; row += nWaves) {
        const float* __restrict__ hr = h + (size_t)row * 64;
        float a = 0.f;
#pragma unroll
        for (int k = 0; k < 64; ++k) a += hr[k] * w[k];
        t[(size_t)row * 64 + lane] = a;
    }
}

// ---- per edge (one wave): acc[dst] += t[src] * inv[dst] ----
__global__ __launch_bounds__(256) void scatter_kernel(
    const float* __restrict__ t, const int* __restrict__ src, const int* __restrict__ dst,
    const float* __restrict__ inv, float* __restrict__ acc, int E)
{
    int e = uni(blockIdx.x * 4 + (threadIdx.x >> 6));
    if (e >= E) return;
    int lane = threadIdx.x & 63;
    int s = src[e], d = dst[e];
    float v = t[(size_t)s * 64 + lane] * inv[d];
    atomicAdd(&acc[(size_t)d * 64 + lane], v);
}

// ---- h_out = relu(h @ Ws + bias + acc) ----
__global__ __launch_bounds__(256) void combine_kernel(
    const float* __restrict__ h, const float* __restrict__ Ws, const float* __restrict__ bias,
    const float* __restrict__ acc, float* __restrict__ hout, int n)
{
    const int lane = threadIdx.x & 63;
    const int wave = blockIdx.x * (blockDim.x >> 6) + (threadIdx.x >> 6);
    const int nWaves = gridDim.x * (blockDim.x >> 6);
    float w[64];
#pragma unroll
    for (int k = 0; k < 64; ++k) w[k] = Ws[k * 64 + lane];
    const float bv = bias[lane];
    for (int row = uni(wave); row < n; row += nWaves) {
        const float* __restrict__ hr = h + (size_t)row * 64;
        float a = bv + acc[(size_t)row * 64 + lane];
#pragma unroll
        for (int k = 0; k < 64; ++k) a += hr[k] * w[k];
        hout[(size_t)row * 64 + lane] = fmaxf(a, 0.f);
    }
}

// ---- column-sum pool: pool[lane] += sum_rows h[row][lane] ----
__global__ __launch_bounds__(256) void pool_kernel(
    const float* __restrict__ h, int n, float* __restrict__ pool)
{
    int lane = threadIdx.x & 63;
    int w = threadIdx.x >> 6;
    float s = 0.f;
    for (int row = blockIdx.x * 4 + w; row < n; row += gridDim.x * 4)
        s += h[(size_t)row * 64 + lane];
    __shared__ float red[256];
    red[threadIdx.x] = s;
    __syncthreads();
    if (threadIdx.x < 64) {
        float t = red[threadIdx.x] + red[threadIdx.x + 64] + red[threadIdx.x + 128] + red[threadIdx.x + 192];
        atomicAdd(&pool[lane], t);
    }
}

// ---- head: out = relu(g @ Wh + bh) @ Wo + bo ----
__global__ void head_kernel(const float* __restrict__ pool,
                            const float* __restrict__ Wh, const float* __restrict__ bh,
                            const float* __restrict__ Wo, const float* __restrict__ bo,
                            float* __restrict__ out)
{
    __shared__ float g[128];
    __shared__ float hid[64];
    int t = threadIdx.x;  // 128 threads
    g[t] = pool[t];
    __syncthreads();
    if (t < 64) {
        float a = bh[t];
        for (int i = 0; i < 128; ++i) a += g[i] * Wh[i * 64 + t];
        hid[t] = fmaxf(a, 0.f);
    }
    __syncthreads();
    if (t < 16) {
        float a = bo[t];
        for (int j = 0; j < 64; ++j) a += hid[j] * Wo[j * 16 + t];
        out[t] = a;
    }
}

extern "C" void kernel_launch(void* const* d_in, const int* in_sizes, int n_in,
                              void* d_out, int out_size, void* d_ws, size_t ws_size,
                              hipStream_t stream)
{
    const float* x_bus   = (const float*)d_in[0];
    const float* x_gen   = (const float*)d_in[1];
    const int* line_src  = (const int*)d_in[2];
    const int* line_dst  = (const int*)d_in[3];
    const int* g2b_src   = (const int*)d_in[4];
    const int* g2b_dst   = (const int*)d_in[5];
    const int* b2g_src   = (const int*)d_in[6];
    const int* b2g_dst   = (const int*)d_in[7];
    const float* Wsb[2]  = {(const float*)d_in[8],  (const float*)d_in[15]};
    const float* Wsg[2]  = {(const float*)d_in[9],  (const float*)d_in[16]};
    const float* Wl[2]   = {(const float*)d_in[10], (const float*)d_in[17]};
    const float* Wg2b[2] = {(const float*)d_in[11], (const float*)d_in[18]};
    const float* Wb2g[2] = {(const float*)d_in[12], (const float*)d_in[19]};
    const float* bsb[2]  = {(const float*)d_in[13], (const float*)d_in[20]};
    const float* bsg[2]  = {(const float*)d_in[14], (const float*)d_in[21]};
    const float* Wh = (const float*)d_in[22];
    const float* bh = (const float*)d_in[23];
    const float* Wo = (const float*)d_in[24];
    const float* bo = (const float*)d_in[25];

    float* w = (float*)d_ws;
    size_t o = 0;
    float* hbA     = w + o; o += (size_t)NB * 64;
    float* hgA     = w + o; o += (size_t)NG * 64;
    float* t_line  = w + o; o += (size_t)NB * 64;
    float* tb_buf  = w + o; o += (size_t)NB * 64;  // t_b2g scratch, then final hb (hbB)
    float* tg_buf  = w + o; o += (size_t)NG * 64;  // t_g2b scratch, then final hg (hgB)
    float* acc_bus = w + o; o += (size_t)NB * 64;
    float* acc_gen = w + o; o += (size_t)NG * 64;
    float* inv_line = w + o; o += NB;
    float* inv_g2b  = w + o; o += NB;
    float* inv_b2g  = w + o; o += NG;
    float* pool     = w + o; o += 128;
    (void)ws_size; (void)in_sizes; (void)n_in; (void)out_size;

    // counts (-> inverse) + pool: one contiguous memset
    hipMemsetAsync(inv_line, 0, (size_t)(2 * NB + NG + 128) * sizeof(float), stream);
    count_kernel<<<(EL + 255) / 256, 256, 0, stream>>>(line_dst, inv_line, EL);
    count_kernel<<<(EX + 255) / 256, 256, 0, stream>>>(g2b_dst, inv_g2b, EX);
    count_kernel<<<(EX + 255) / 256, 256, 0, stream>>>(b2g_dst, inv_b2g, EX);
    inv_kernel<<<(2 * NB + NG + 255) / 256, 256, 0, stream>>>(inv_line, 2 * NB + NG);

    const float* hb_in = x_bus;
    const float* hg_in = x_gen;
    float* hb_out = hbA;
    float* hg_out = hgA;
    for (int l = 0; l < 2; ++l) {
        hipMemsetAsync(acc_bus, 0, (size_t)NB * 64 * sizeof(float), stream);
        hipMemsetAsync(acc_gen, 0, (size_t)NG * 64 * sizeof(float), stream);
        transform2_kernel<<<1024, 256, 0, stream>>>(hb_in, Wl[l], Wb2g[l], t_line, tb_buf, NB);
        transform1_kernel<<<256, 256, 0, stream>>>(hg_in, Wg2b[l], tg_buf, NG);
        scatter_kernel<<<(EL + 3) / 4, 256, 0, stream>>>(t_line, line_src, line_dst, inv_line, acc_bus, EL);
        scatter_kernel<<<(EX + 3) / 4, 256, 0, stream>>>(tg_buf, g2b_src, g2b_dst, inv_g2b, acc_bus, EX);
        scatter_kernel<<<(EX + 3) / 4, 256, 0, stream>>>(tb_buf, b2g_src, b2g_dst, inv_b2g, acc_gen, EX);
        combine_kernel<<<1024, 256, 0, stream>>>(hb_in, Wsb[l], bsb[l], acc_bus, hb_out, NB);
        combine_kernel<<<256, 256, 0, stream>>>(hg_in, Wsg[l], bsg[l], acc_gen, hg_out, NG);
        hb_in = hb_out; hb_out = tb_buf;  // layer 1 writes final hb into tb_buf
        hg_in = hg_out; hg_out = tg_buf;
    }
    pool_kernel<<<512, 256, 0, stream>>>(hb_in, NB, pool);
    pool_kernel<<<512, 256, 0, stream>>>(hg_in, NG, pool + 64);
    head_kernel<<<1, 128, 0, stream>>>(pool, Wh, bh, Wo, bo, (float*)d_out);
}